// Round 4
// 998.901 us; speedup vs baseline: 1.0022x; 1.0022x over previous
//
#include <hip/hip_runtime.h>

#define N_ROWS 262144
#define NF 512
#define ND 8
#define F4 128            // float4 per row
#define EPSV 1e-5f

#define G1 256
#define B1 512
#define ROWS_PER_B1 (N_ROWS / G1)    // 1024
#define PSTRIDE 8448                  // floats per partial group (8200 used, padded)

#define G3 1024
#define B3 512
#define ROWS_PER_B3 (N_ROWS / G3)    // 256

// native clang vector for nontemporal builtin (HIP float4 is a class type,
// which __builtin_nontemporal_store rejects)
typedef float f32x4 __attribute__((ext_vector_type(4)));

static __device__ __forceinline__ void nt_store4(float4 v, float4* p) {
  f32x4 w;
  w.x = v.x; w.y = v.y; w.z = v.z; w.w = v.w;
  __builtin_nontemporal_store(w, (f32x4*)p);
}

// Accumulate one float4 into the (compile-time) domain-D register accumulators.
#define ACC1(D, V)                                              \
    sum[D][0] += (V).x; sq[D][0] = fmaf((V).x, (V).x, sq[D][0]); \
    sum[D][1] += (V).y; sq[D][1] = fmaf((V).y, (V).y, sq[D][1]); \
    sum[D][2] += (V).z; sq[D][2] = fmaf((V).z, (V).z, sq[D][2]); \
    sum[D][3] += (V).w; sq[D][3] = fmaf((V).w, (V).w, sq[D][3]); \
    cnt[D] += cinc;

// dom is wave-uniform (readfirstlane) -> scalar branch, no divergence.
#define ACCUM(DD, V) switch (DD) {            \
    case 0: { ACC1(0, V) } break;             \
    case 1: { ACC1(1, V) } break;             \
    case 2: { ACC1(2, V) } break;             \
    case 3: { ACC1(3, V) } break;             \
    case 4: { ACC1(4, V) } break;             \
    case 5: { ACC1(5, V) } break;             \
    case 6: { ACC1(6, V) } break;             \
    default: { ACC1(7, V) } break; }

// ---------------- kernel 1: per-block partial sums (no atomics) --------------
// x loads stay NORMAL (allocate in L3): k1 streams rows 0..N forward, leaving
// the tail ~256MB of x resident in Infinity Cache for k3's reversed pass.
__global__ __launch_bounds__(B1, 2) void k1_partial(
    const float* __restrict__ x, const int* __restrict__ y,
    float* __restrict__ part /* d_out used as scratch */) {
  __shared__ float sSum[4][ND][F4];
  __shared__ float sSq[4][ND][F4];
  __shared__ float sCnt[ND];
  __shared__ int sY[ROWS_PER_B1];   // 4 KB: row->domain, off the vmcnt chain

  float sum[ND][4];
  float sq[ND][4];
  float cnt[ND];
#pragma unroll
  for (int d = 0; d < ND; ++d) {
    cnt[d] = 0.0f;
#pragma unroll
    for (int j = 0; j < 4; ++j) { sum[d][j] = 0.0f; sq[d][j] = 0.0f; }
  }

  const int tid = threadIdx.x;
  const int f4 = tid & (F4 - 1);
  const int rg = tid >> 7;               // 0..3
  const float cinc = (f4 == 0) ? 1.0f : 0.0f;  // count each row exactly once
  const float4* __restrict__ x4 = (const float4*)x;
  const int rowBase = blockIdx.x * ROWS_PER_B1;

  // stage this block's y chunk in LDS (coalesced, once)
  for (int i = tid; i < ROWS_PER_B1; i += B1) sY[i] = y[rowBase + i];
  __syncthreads();

  for (int r0 = 0; r0 < ROWS_PER_B1; r0 += 16) {
    const int lr = r0 + rg;
    const int r = rowBase + lr;
    // issue all 4 row loads first (ILP: 4 outstanding dwordx4 per thread)
    float4 v0 = x4[(size_t)(r +  0) * F4 + f4];
    float4 v1 = x4[(size_t)(r +  4) * F4 + f4];
    float4 v2 = x4[(size_t)(r +  8) * F4 + f4];
    float4 v3 = x4[(size_t)(r + 12) * F4 + f4];
    // domain ids from LDS: switch resolves on lgkmcnt while x loads fly
    const int d0 = __builtin_amdgcn_readfirstlane(sY[lr +  0]);
    const int d1 = __builtin_amdgcn_readfirstlane(sY[lr +  4]);
    const int d2 = __builtin_amdgcn_readfirstlane(sY[lr +  8]);
    const int d3 = __builtin_amdgcn_readfirstlane(sY[lr + 12]);
    ACCUM(d0, v0)
    ACCUM(d1, v1)
    ACCUM(d2, v2)
    ACCUM(d3, v3)
  }

  // 4-phase LDS merge across rg groups (cross-wave, so LDS is required)
  for (int p = 0; p < 4; ++p) {
    if (rg == p) {
#pragma unroll
      for (int d = 0; d < ND; ++d) {
#pragma unroll
        for (int j = 0; j < 4; ++j) {
          if (p == 0) { sSum[j][d][f4] = sum[d][j]; sSq[j][d][f4] = sq[d][j]; }
          else        { sSum[j][d][f4] += sum[d][j]; sSq[j][d][f4] += sq[d][j]; }
        }
        if (f4 == 0) {
          if (p == 0) sCnt[d] = cnt[d]; else sCnt[d] += cnt[d];
        }
      }
    }
    __syncthreads();
  }

  // coalesced flush: [0,4096) sums, [4096,8192) sumsq, [8192,8200) counts
  float* __restrict__ pb = part + (size_t)blockIdx.x * PSTRIDE;
  for (int i = tid; i < 8200; i += B1) {
    float v;
    if (i < 4096) {
      const int d = i >> 9, f = i & 511;
      v = sSum[f & 3][d][f >> 2];
    } else if (i < 8192) {
      const int k = i - 4096;
      const int d = k >> 9, f = k & 511;
      v = sSq[f & 3][d][f >> 2];
    } else {
      v = sCnt[i - 8192];
    }
    pb[i] = v;
  }
}

// ------- kernel 2: reduce 256 partials AND finalize scale/shift (fused) ------
__global__ void k2_finalize(const float* __restrict__ part,
                            const float* __restrict__ gamma,
                            const float* __restrict__ beta,
                            float* __restrict__ ss /* ws: scale[4096], shift[4096] */) {
  const int i = blockIdx.x * 128 + threadIdx.x;  // 0..4095 (d*512 + f)
  const int d = i >> 9;
  // 4-way split accumulators: loads overlap, adds stay statically indexed
  float sa[4] = {0.f, 0.f, 0.f, 0.f};
  float qa[4] = {0.f, 0.f, 0.f, 0.f};
  float ca[4] = {0.f, 0.f, 0.f, 0.f};
  for (int b = 0; b < G1; b += 4) {
#pragma unroll
    for (int u = 0; u < 4; ++u) {
      const float* __restrict__ p = part + (size_t)(b + u) * PSTRIDE;
      sa[u] += p[i];
      qa[u] += p[4096 + i];
      ca[u] += p[8192 + d];
    }
  }
  const float s = (sa[0] + sa[1]) + (sa[2] + sa[3]);
  const float q = (qa[0] + qa[1]) + (qa[2] + qa[3]);
  const float c = (ca[0] + ca[1]) + (ca[2] + ca[3]);

  const float safe = fmaxf(c, 1.0f);
  const float mean = s / safe;
  const float var = q / safe - mean * mean;
  const bool ub = c > 1.0f;                 // count==1 -> eval mode (mean 0, var 1)
  const float mean_e = ub ? mean : 0.0f;
  const float var_e = ub ? var : 1.0f;
  const float inv = rsqrtf(var_e + EPSV);
  float scale = gamma[i] * inv;
  float shift = beta[i] - scale * mean_e;
  if (!(c > 0.0f)) { scale = 0.0f; shift = 0.0f; }  // count==0 -> output zeros
  ss[i] = scale;
  ss[4096 + i] = shift;
}

// ---------------- kernel 3: normalize ---------------------------------------
// REVERSED block->row mapping: first-dispatched blocks read the x tail that k1
// left resident in L3. NONTEMPORAL stores: don't let the 512MB out stream evict
// that residency. scale/shift + y staged in LDS: no L1-thrashed gathers.
__global__ __launch_bounds__(B3, 2) void k3_normalize(
    const float* __restrict__ x, const int* __restrict__ y,
    const float* __restrict__ ss, float* __restrict__ out) {
  __shared__ float4 sS[ND * F4];   // 16 KB scale
  __shared__ float4 sT[ND * F4];   // 16 KB shift
  __shared__ int sy[ROWS_PER_B3];  // 1 KB row->domain

  const int tid = threadIdx.x;
  const int rowBase = (G3 - 1 - (int)blockIdx.x) * ROWS_PER_B3;

  const float4* __restrict__ ssv = (const float4*)ss;
  sS[tid]       = ssv[tid];
  sS[tid + 512] = ssv[tid + 512];
  sT[tid]       = ssv[1024 + tid];
  sT[tid + 512] = ssv[1536 + tid];
  if (tid < ROWS_PER_B3) sy[tid] = y[rowBase + tid];
  __syncthreads();

  const int f4 = tid & (F4 - 1);
  const int rg = tid >> 7;  // 0..3
  const float4* __restrict__ x4 = (const float4*)x;
  float4* __restrict__ o4 = (float4*)out;

  for (int r0 = 0; r0 < ROWS_PER_B3; r0 += 16) {
    const int lr = r0 + rg;
    const size_t g = (size_t)(rowBase + lr) * F4 + f4;
    // 4 row loads in flight
    float4 v0 = x4[g];
    float4 v1 = x4[g +  4 * F4];
    float4 v2 = x4[g +  8 * F4];
    float4 v3 = x4[g + 12 * F4];
    const int d0 = sy[lr];
    const int d1 = sy[lr + 4];
    const int d2 = sy[lr + 8];
    const int d3 = sy[lr + 12];
    float4 s0 = sS[d0 * F4 + f4], t0 = sT[d0 * F4 + f4];
    float4 s1 = sS[d1 * F4 + f4], t1 = sT[d1 * F4 + f4];
    float4 s2 = sS[d2 * F4 + f4], t2 = sT[d2 * F4 + f4];
    float4 s3 = sS[d3 * F4 + f4], t3 = sT[d3 * F4 + f4];
    float4 o0, o1, o2, o3;
    o0.x = fmaf(s0.x, v0.x, t0.x); o0.y = fmaf(s0.y, v0.y, t0.y);
    o0.z = fmaf(s0.z, v0.z, t0.z); o0.w = fmaf(s0.w, v0.w, t0.w);
    o1.x = fmaf(s1.x, v1.x, t1.x); o1.y = fmaf(s1.y, v1.y, t1.y);
    o1.z = fmaf(s1.z, v1.z, t1.z); o1.w = fmaf(s1.w, v1.w, t1.w);
    o2.x = fmaf(s2.x, v2.x, t2.x); o2.y = fmaf(s2.y, v2.y, t2.y);
    o2.z = fmaf(s2.z, v2.z, t2.z); o2.w = fmaf(s2.w, v2.w, t2.w);
    o3.x = fmaf(s3.x, v3.x, t3.x); o3.y = fmaf(s3.y, v3.y, t3.y);
    o3.z = fmaf(s3.z, v3.z, t3.z); o3.w = fmaf(s3.w, v3.w, t3.w);
    nt_store4(o0, &o4[g]);
    nt_store4(o1, &o4[g +  4 * F4]);
    nt_store4(o2, &o4[g +  8 * F4]);
    nt_store4(o3, &o4[g + 12 * F4]);
  }
}

extern "C" void kernel_launch(void* const* d_in, const int* in_sizes, int n_in,
                              void* d_out, int out_size, void* d_ws, size_t ws_size,
                              hipStream_t stream) {
  const float* x     = (const float*)d_in[0];
  const int*   y     = (const int*)d_in[1];
  const float* gamma = (const float*)d_in[2];
  const float* beta  = (const float*)d_in[3];
  float* out = (float*)d_out;
  float* ws  = (float*)d_ws;  // needs only 8192 floats (32 KB)

  // d_out doubles as scratch for partials; k3 overwrites all of it afterwards.
  float* p1 = out;                              // 256 * 8448 floats (~8.6 MB)

  k1_partial<<<G1, B1, 0, stream>>>(x, y, p1);
  k2_finalize<<<32, 128, 0, stream>>>(p1, gamma, beta, ws);
  k3_normalize<<<G3, B3, 0, stream>>>(x, y, ws, out);
}